// Round 6
// baseline (402.472 us; speedup 1.0000x reference)
//
#include <hip/hip_runtime.h>
#include <cstddef>
#include <cstdint>

// LinearAttention — bf16 MFMA, global_load_lds staging, XOR-swizzled LDS.
// B=4 L=4096 D=1024 H=16 d=64 M=128 (2M=256).
// K0 fused convert (grid-stride) -> K1 fused QKV GEMM (128^2, proven)
// -> K2 fourier(k)+kv outer (DOUBLE-BUFFERED stage, counted vmcnt)
// -> K2.5 reduce+transpose -> K3 fourier(q)+attn (PREFETCHED kvT+q, counted
// vmcnt) -> K4 out GEMM.
//
// ws layout (bytes):
//   qb     @ 0          33.55MB  bf16 [16384][1024]
//   kb     @ 33554432   33.55MB  bf16 [16384][1024]   (reused as attnb)
//   vT     @ 67108864   33.55MB  bf16 [(b*16+h)*64+d][4096]  (reused as kvT)
//   xb     @ 100663296  33.55MB  bf16 [16384][1024]   (kv_part f32 32MB overlays after K1)
//   Wqkvb  @ 134217728   6.29MB  bf16 [3072][1024]
//   Wob    @ 140509184   2.10MB  bf16 [1024][1024]
//   projT  @ 142606336   16KB    bf16 [128 m][64 d]

typedef __attribute__((ext_vector_type(8))) short s8v;   // 8 x bf16 (16B)
typedef __attribute__((ext_vector_type(4))) short s4v;   // 4 x bf16 (8B)
typedef __attribute__((ext_vector_type(4))) float f32x4; // MFMA acc

#define MFMA_BF16(a, b, c) __builtin_amdgcn_mfma_f32_16x16x32_bf16((a), (b), (c), 0, 0, 0)

#define P_SCALE 0.125f                 // 1/sqrt(64)
#define F_SCALE 0.08838834764831845f   // 1/sqrt(128)

static __device__ __forceinline__ unsigned short f2bf(float f) {
  unsigned int u = __float_as_uint(f);
  u += 0x7fffu + ((u >> 16) & 1u);  // RNE
  return (unsigned short)(u >> 16);
}

// async 16B global->LDS (DMA; LDS dest = wave-uniform base + lane*16)
static __device__ __forceinline__ void gload_lds16(const void* g, void* l) {
  __builtin_amdgcn_global_load_lds(
      (const __attribute__((address_space(1))) unsigned int*)g,
      (__attribute__((address_space(3))) unsigned int*)l, 16, 0, 0);
}

#define VMC(n) asm volatile("s_waitcnt vmcnt(" #n ")" ::: "memory")
#define LGKM0 asm volatile("s_waitcnt lgkmcnt(0)" ::: "memory")
#define RBAR  { __builtin_amdgcn_s_barrier(); __builtin_amdgcn_sched_barrier(0); }

// ---------------------------------------------------------------------------
// K0: fused fp32->bf16 convert, grid-stride (2048 blocks x 256 thr).
// ---------------------------------------------------------------------------
__global__ void conv_all_kernel(const float* __restrict__ x,
                                const float* __restrict__ Wq, const float* __restrict__ Wk,
                                const float* __restrict__ Wv, const float* __restrict__ Wo,
                                const float* __restrict__ proj,
                                short* __restrict__ xb, short* __restrict__ Wqkvb,
                                short* __restrict__ Wob, short* __restrict__ projT) {
  const int T = blockIdx.x * 256 + threadIdx.x;  // 0..524287
  for (int u = T; u < 5244928; u += 524288) {
    if (u < 4194304) {
      float4 f = ((const float4*)x)[u];
      s4v v;
      v[0] = (short)f2bf(f.x); v[1] = (short)f2bf(f.y);
      v[2] = (short)f2bf(f.z); v[3] = (short)f2bf(f.w);
      ((s4v*)xb)[u] = v;
    } else if (u < 5242880) {
      int vi = u - 4194304;
      int wi = vi >> 18;           // 0..3 (Wq,Wk,Wv,Wo), 262144 float4 each
      int off = vi & 262143;
      const float* src = (wi == 0) ? Wq : (wi == 1) ? Wk : (wi == 2) ? Wv : Wo;
      short* dst = (wi < 3) ? (Wqkvb + (size_t)wi * 1048576) : Wob;
      float4 f = ((const float4*)src)[off];
      s4v v;
      v[0] = (short)f2bf(f.x); v[1] = (short)f2bf(f.y);
      v[2] = (short)f2bf(f.z); v[3] = (short)f2bf(f.w);
      ((s4v*)dst)[off] = v;
    } else {
      int vi = u - 5242880;        // proj [64 d][128 m]: 32 float4 per row
      int d = vi >> 5, m4 = (vi & 31) * 4;
      float4 f = ((const float4*)proj)[vi];
      projT[(m4 + 0) * 64 + d] = (short)f2bf(f.x);
      projT[(m4 + 1) * 64 + d] = (short)f2bf(f.y);
      projT[(m4 + 2) * 64 + d] = (short)f2bf(f.z);
      projT[(m4 + 3) * 64 + d] = (short)f2bf(f.w);
    }
  }
}

// ---------------------------------------------------------------------------
// K1: qkv = xb @ Wqkv^T + bias. 128x128 tile, BK=64, bf16 MFMA. (Proven:
// ~104us, 45% MfmaUtil; 256^2 8-phase ports measured SLOWER: 138/110us.)
// grid (128 row-tiles, 24 col-tiles). bn 0-7: q, 8-15: k, 16-23: v.
// ---------------------------------------------------------------------------
__global__ void qkv_gemm_kernel(const short* __restrict__ xb,
                                const short* __restrict__ Wqkv,
                                const float* __restrict__ bq_, const float* __restrict__ bk_,
                                const float* __restrict__ bv_,
                                short* __restrict__ qb, short* __restrict__ kb,
                                short* __restrict__ vT) {
  __shared__ __align__(16) short smem[17408];  // A[128][64]+B[128][64]; epi image [128][136]
  short* Al = smem;
  short* Bl = smem + 8192;

  const int t = threadIdx.x;
  const int bm = blockIdx.x, bn = blockIdx.y;
  const int row0 = bm * 128, n0 = bn * 128;
  const int lane = t & 63, w = t >> 6;
  const int wm = w & 1, wn = w >> 1;
  const int l15 = lane & 15, lq = lane >> 4;
  const int sx = (l15 & 7) * 8;   // fragment-read swizzle term (in shorts)

  f32x4 acc[4][4];
#pragma unroll
  for (int i = 0; i < 4; ++i)
#pragma unroll
    for (int j = 0; j < 4; ++j) acc[i][j] = (f32x4){0.f, 0.f, 0.f, 0.f};

  for (int k0 = 0; k0 < 1024; k0 += 64) {
#pragma unroll
    for (int i = 0; i < 4; ++i) {
      int c = t + i * 256;                 // chunk 0..1023
      int r = c >> 3, cl = c & 7;
      int cg = cl ^ (r & 7);               // permuted global chunk
      gload_lds16(xb   + (size_t)(row0 + r) * 1024 + k0 + cg * 8, Al + c * 8);
      gload_lds16(Wqkv + (size_t)(n0 + r) * 1024 + k0 + cg * 8, Bl + c * 8);
    }
    __syncthreads();
#pragma unroll
    for (int ks = 0; ks < 2; ++ks) {
      const int kb8 = (ks * 4 + lq) * 8;
      s8v af[4], bfr[4];
#pragma unroll
      for (int i = 0; i < 4; ++i)
        af[i] = *(s8v*)&Al[(wm * 64 + i * 16 + l15) * 64 + (kb8 ^ sx)];
#pragma unroll
      for (int j = 0; j < 4; ++j)
        bfr[j] = *(s8v*)&Bl[(wn * 64 + j * 16 + l15) * 64 + (kb8 ^ sx)];
#pragma unroll
      for (int i = 0; i < 4; ++i)
#pragma unroll
        for (int j = 0; j < 4; ++j)
          acc[i][j] = MFMA_BF16(af[i], bfr[j], acc[i][j]);
    }
    __syncthreads();
  }

  const int region = bn >> 3;  // 0 q, 1 k, 2 v
  if (region < 2) {
    const float* bias = (region == 0) ? bq_ : bk_;
    short* IM = smem;  // [128][136] natural image
#pragma unroll
    for (int j = 0; j < 4; ++j) {
      int cl = wn * 64 + j * 16 + l15;
      float bsv = bias[(n0 & 1023) + cl];
#pragma unroll
      for (int i = 0; i < 4; ++i)
#pragma unroll
        for (int r = 0; r < 4; ++r)
          IM[(wm * 64 + i * 16 + lq * 4 + r) * 136 + cl] = (short)f2bf(acc[i][j][r] + bsv);
    }
    __syncthreads();
    short* dst = (region == 0) ? qb : kb;
#pragma unroll
    for (int i = 0; i < 8; ++i) {
      int c = t + i * 256;
      int r = c >> 4, cc = c & 15;
      *(s8v*)&dst[(size_t)(row0 + r) * 1024 + (n0 & 1023) + cc * 8] =
          *(s8v*)&IM[r * 136 + cc * 8];
    }
  } else {
    short* IM = smem;  // [128 col][136] transposed image
#pragma unroll
    for (int j = 0; j < 4; ++j) {
      int cl = wn * 64 + j * 16 + l15;
      float bsv = bv_[(n0 - 2048) + cl];
#pragma unroll
      for (int i = 0; i < 4; ++i) {
        s4v pk;
#pragma unroll
        for (int r = 0; r < 4; ++r) pk[r] = (short)f2bf(acc[i][j][r] + bsv);
        *(s4v*)&IM[cl * 136 + wm * 64 + i * 16 + lq * 4] = pk;
      }
    }
    __syncthreads();
    const int b = row0 >> 12;
    const int l0 = (bm & 31) * 128;
#pragma unroll
    for (int i = 0; i < 8; ++i) {
      int c = t + i * 256;
      int ci = c >> 4, cc = c & 15;
      int cv = (bn - 16) * 128 + ci;      // 0..1023
      int grow = (b * 16 + (cv >> 6)) * 64 + (cv & 63);
      *(s8v*)&vT[(size_t)grow * 4096 + l0 + cc * 8] = *(s8v*)&IM[ci * 136 + cc * 8];
    }
  }
}

// ---------------------------------------------------------------------------
// K2: per (b,h,512-row chunk): fourier(k) -> k' ; kv_part[chunk] = k'^T @ v.
// DOUBLE-BUFFERED staging: issue step s+1's 4 gloads before vmcnt(4)-waiting
// on step s; raw s_barrier (no vmcnt-0 drain in loop). grid 512.
// LDS 64KB: kt[2][64][64] + vt[2][64][64] + kpT[256][64] (XOR-chunk swizzle).
// kv_part layout: [chunk 8][bh 64][m 256][d 64] f32 (32MB, overlays dead xb).
// ---------------------------------------------------------------------------
__global__ void kv_accum_kernel(const short* __restrict__ kb, const short* __restrict__ vT,
                                const short* __restrict__ projT, float* __restrict__ kv) {
  __shared__ __align__(16) short smem[32768];  // 64KB exactly
  short* kt = smem;            // [2][4096]
  short* vt = smem + 8192;     // [2][4096]
  short* kpT = smem + 16384;   // [256][64] swizzled

  const int t = threadIdx.x;
  const int bid = blockIdx.x;
  const int chunk = bid & 7, h = (bid >> 3) & 15, b = bid >> 7;
  const int lane = t & 63, w = t >> 6;
  const int l15 = lane & 15, lq = lane >> 4;
  const int sx = (l15 & 7) * 8;

  s8v pf[8][2];
#pragma unroll
  for (int nt = 0; nt < 8; ++nt)
#pragma unroll
    for (int ks = 0; ks < 2; ++ks)
      pf[nt][ks] = *(const s8v*)(projT + (size_t)(nt * 16 + l15) * 64 + ks * 32 + lq * 8);

  f32x4 kvacc[4][4];
#pragma unroll
  for (int i = 0; i < 4; ++i)
#pragma unroll
    for (int j = 0; j < 4; ++j) kvacc[i][j] = (f32x4){0.f, 0.f, 0.f, 0.f};

#define STAGE_KV(pp, ss) {                                                       \
    const int l0s = chunk * 512 + (ss) * 64;                                     \
    _Pragma("unroll") for (int i = 0; i < 2; ++i) {                              \
      int c = t + i * 256; int r = c >> 3, cl = c & 7, cg = cl ^ (r & 7);        \
      gload_lds16(kb + (size_t)(b * 4096 + l0s + r) * 1024 + h * 64 + cg * 8,    \
                  kt + (pp) * 4096 + c * 8);                                     \
      gload_lds16(vT + (size_t)((b * 16 + h) * 64 + r) * 4096 + l0s + cg * 8,    \
                  vt + (pp) * 4096 + c * 8);                                     \
    } }

  int p = 0;
  STAGE_KV(0, 0);
  for (int s = 0; s < 8; ++s) {
    if (s < 7) { STAGE_KV(p ^ 1, s + 1); VMC(4); } else { VMC(0); }
    RBAR;  // buf p staged & visible; next-step loads stay in flight

    // fourier: wave w rows w*16..+15 (reads kt[p])
    f32x4 pacc[8];
#pragma unroll
    for (int nt = 0; nt < 8; ++nt) pacc[nt] = (f32x4){0.f, 0.f, 0.f, 0.f};
#pragma unroll
    for (int ks = 0; ks < 2; ++ks) {
      const int kb8 = (ks * 4 + lq) * 8;
      s8v af = *(s8v*)&kt[p * 4096 + (w * 16 + l15) * 64 + (kb8 ^ sx)];
#pragma unroll
      for (int nt = 0; nt < 8; ++nt) pacc[nt] = MFMA_BF16(af, pf[nt][ks], pacc[nt]);
    }
    {
      const int cidx = w * 2 + (lq >> 1);       // (w*16+lq*4)>>3
      const int within = (lq & 1) * 4;
#pragma unroll
      for (int nt = 0; nt < 8; ++nt) {
        s4v cp, sp;
#pragma unroll
        for (int r = 0; r < 4; ++r) {
          float pv = pacc[nt][r] * P_SCALE;
          float sv, cv;
          __sincosf(pv, &sv, &cv);
          cp[r] = (short)f2bf(cv * F_SCALE);
          sp[r] = (short)f2bf(sv * F_SCALE);
        }
        int m = nt * 16 + l15;
        int col = ((cidx ^ (m & 7)) << 3) + within;
        *(s4v*)&kpT[m * 64 + col] = cp;
        *(s4v*)&kpT[(m + 128) * 64 + col] = sp;
      }
    }
    LGKM0;
    RBAR;  // kpT published

    // kv MFMA: wave w m-range w*64..+63 (reads kpT swizzled + vt[p])
#pragma unroll
    for (int ks = 0; ks < 2; ++ks) {
      const int kb8 = (ks * 4 + lq) * 8;
      s8v af2[4], bf4[4];
#pragma unroll
      for (int i = 0; i < 4; ++i)
        af2[i] = *(s8v*)&kpT[(w * 64 + i * 16 + l15) * 64 +
                             (((ks * 4 + lq) ^ (l15 & 7)) * 8)];
#pragma unroll
      for (int j = 0; j < 4; ++j)
        bf4[j] = *(s8v*)&vt[p * 4096 + (j * 16 + l15) * 64 + (kb8 ^ sx)];
#pragma unroll
      for (int i = 0; i < 4; ++i)
#pragma unroll
        for (int j = 0; j < 4; ++j)
          kvacc[i][j] = MFMA_BF16(af2[i], bf4[j], kvacc[i][j]);
    }
    RBAR;  // protect kpT + buf p before next iteration rewrites
    p ^= 1;
  }
#undef STAGE_KV

  // private partial: kv_part[chunk][bh][m][d], plain coalesced stores
  float* kvb = kv + (size_t)chunk * 1048576 + ((size_t)(b * 16 + h) << 14);
#pragma unroll
  for (int i = 0; i < 4; ++i)
#pragma unroll
    for (int j = 0; j < 4; ++j)
#pragma unroll
      for (int r = 0; r < 4; ++r) {
        int m = w * 64 + i * 16 + lq * 4 + r;
        int d = j * 16 + l15;
        kvb[(size_t)m * 64 + d] = kvacc[i][j][r];
      }
}

// ---------------------------------------------------------------------------
// K2.5: reduce 8 kv partials f32 -> kvT bf16 [bh*64+d][256]. grid (64,4).
// ---------------------------------------------------------------------------
__global__ void kvT_kernel(const float* __restrict__ kvp, short* __restrict__ kvT) {
  __shared__ __align__(16) short im[4608];  // [64 d][72]
  const int t = threadIdx.x;
  const int bh = blockIdx.x, mc = blockIdx.y;
  const float* base = kvp + (size_t)bh * 16384 + (size_t)mc * 4096;
#pragma unroll
  for (int i = 0; i < 4; ++i) {
    int idx4 = t + i * 256;                // 1024 float4s = [64 m][64 d]
    int mm = idx4 >> 4, d4 = (idx4 & 15) * 4;
    float4 s = {0.f, 0.f, 0.f, 0.f};
#pragma unroll
    for (int c = 0; c < 8; ++c) {
      float4 v = *(const float4*)(base + (size_t)c * 1048576 + mm * 64 + d4);
      s.x += v.x; s.y += v.y; s.z += v.z; s.w += v.w;
    }
    im[(d4 + 0) * 72 + mm] = (short)f2bf(s.x);
    im[(d4 + 1) * 72 + mm] = (short)f2bf(s.y);
    im[(d4 + 2) * 72 + mm] = (short)f2bf(s.z);
    im[(d4 + 3) * 72 + mm] = (short)f2bf(s.w);
  }
  __syncthreads();
#pragma unroll
  for (int i = 0; i < 2; ++i) {
    int c = t + i * 256;                   // 512 stores x 16B = [64 d][64 m]
    int d = c >> 3, mm8 = (c & 7) * 8;
    *(s8v*)&kvT[(size_t)(bh * 64 + d) * 256 + mc * 64 + mm8] = *(s8v*)&im[d * 72 + mm8];
  }
}

// ---------------------------------------------------------------------------
// K3: fourier(q) + attn = q' @ kv, per (64-row tile, head). grid (256,16).
// PREFETCH: q + BOTH kvT halves issued up front; vmcnt(8)/(4)/(0) counted
// waits; 3 raw barriers in main flow. LDS 57KB: qt+qA+kvt[2][64][128].
// ---------------------------------------------------------------------------
__global__ void attn_kernel(const short* __restrict__ qb, const short* __restrict__ projT,
                            const short* __restrict__ kvT, short* __restrict__ attnb) {
  __shared__ __align__(16) short smem[29184];  // qt 4096 + qA 8704 + kvt 2x8192
  short* qt = smem;
  short* qA = smem + 4096;      // [64][136]
  short* kvt = smem + 12800;    // [2][64][128]

  const int t = threadIdx.x;
  const int rt = blockIdx.x, h = blockIdx.y;
  const int row0 = rt * 64;
  const int b = row0 >> 12;
  const int lane = t & 63, w = t >> 6;
  const int l15 = lane & 15, lq = lane >> 4;
  const int sx = (l15 & 7) * 8;

  s8v pf[8][2];
#pragma unroll
  for (int nt = 0; nt < 8; ++nt)
#pragma unroll
    for (int ks = 0; ks < 2; ++ks)
      pf[nt][ks] = *(const s8v*)(projT + (size_t)(nt * 16 + l15) * 64 + ks * 32 + lq * 8);

  // --- issue ALL stages up front: q (2 loads), kvt half0 (4), half1 (4) ---
#pragma unroll
  for (int i = 0; i < 2; ++i) {
    int c = t + i * 256;
    int r = c >> 3, cl = c & 7;
    int cg = cl ^ (r & 7);
    gload_lds16(qb + (size_t)(row0 + r) * 1024 + h * 64 + cg * 8, qt + c * 8);
  }
#pragma unroll
  for (int half = 0; half < 2; ++half)
#pragma unroll
    for (int i = 0; i < 4; ++i) {
      int c = t + i * 256;                 // chunk 0..1023
      int d = c >> 4, cl = c & 15;
      int cg = cl ^ (d & 15);
      gload_lds16(kvT + (size_t)((b * 16 + h) * 64 + d) * 256 + half * 128 + cg * 8,
                  kvt + half * 8192 + c * 8);
    }
  VMC(8);   // q's 2 loads retired (8 kv loads still in flight)
  RBAR;

  f32x4 pacc[8];
#pragma unroll
  for (int nt = 0; nt < 8; ++nt) pacc[nt] = (f32x4){0.f, 0.f, 0.f, 0.f};
#pragma unroll
  for (int ks = 0; ks < 2; ++ks) {
    const int kb8 = (ks * 4 + lq) * 8;
    s8v af = *(s8v*)&qt[(w * 16 + l15) * 64 + (kb8 ^ sx)];
#pragma unroll
    for (int nt = 0; nt < 8; ++nt) pacc[nt] = MFMA_BF16(af, pf[nt][ks], pacc[nt]);
  }

  f32x4 aacc[4];
#pragma unroll
  for (int j = 0; j < 4; ++j) aacc[j] = (f32x4){0.f, 0.f, 0.f, 0.f};

#pragma unroll
  for (int half = 0; half < 2; ++half) {
    // q' half -> qA [64][136] (wave-private rows; no barrier needed)
#pragma unroll
    for (int nt = 0; nt < 8; ++nt)
#pragma unroll
      for (int r = 0; r < 4; ++r) {
        float p = pacc[nt][r] * P_SCALE;
        float fv = (half == 0) ? __cosf(p) : __sinf(p);
        qA[(w * 16 + lq * 4 + r) * 136 + nt * 16 + l15] = (short)f2bf(fv * F_SCALE);
      }
    if (half == 0) { VMC(4); } else { VMC(0); }
    RBAR;  // kvt[half] staged by all waves & visible
#pragma unroll
    for (int ks = 0; ks < 4; ++ks) {
      s8v af = *(s8v*)&qA[(w * 16 + l15) * 136 + ks * 32 + lq * 8];
#pragma unroll
      for (int j = 0; j < 4; ++j) {
        int row = j * 16 + l15;
        s8v bf4 = *(s8v*)&kvt[half * 8192 + row * 128 + (((ks * 4 + lq) ^ l15) * 8)];
        aacc[j] = MFMA_BF16(af, bf4, aacc[j]);
      }
    }
  }

  // epilogue image at smem base [64][72] (overlaps qt/qA head — barrier first)
  __syncthreads();
#pragma unroll
  for (int j = 0; j < 4; ++j)
#pragma unroll
    for (int r = 0; r < 4; ++r)
      smem[(w * 16 + lq * 4 + r) * 72 + j * 16 + l15] = (short)f2bf(aacc[j][r]);
  __syncthreads();
#pragma unroll
  for (int i = 0; i < 2; ++i) {
    int c = t + i * 256;
    int r = c >> 3, cc = c & 7;
    *(s8v*)&attnb[(size_t)(row0 + r) * 1024 + h * 64 + cc * 8] = *(s8v*)&smem[r * 72 + cc * 8];
  }
}

// ---------------------------------------------------------------------------
// K4: out = attn @ Wo^T + bo. fp32 out. grid (128, 8).
// ---------------------------------------------------------------------------
__global__ void out_gemm_kernel(const short* __restrict__ attnb, const short* __restrict__ Wob,
                                const float* __restrict__ bo_, float* __restrict__ out) {
  __shared__ __align__(16) short smem[16384];
  short* Al = smem;
  short* Bl = smem + 8192;

  const int t = threadIdx.x;
  const int bm = blockIdx.x, bn = blockIdx.y;
  const int row0 = bm * 128, n0 = bn * 128;
  const int lane = t & 63, w = t >> 6;
  const int wm = w & 1, wn = w >> 1;
  const int l15 = lane & 15, lq = lane >> 4;
  const int sx = (l15 & 7) * 8;

  f32x4 acc[4][4];
#pragma unroll
  for (int i = 0; i < 4; ++i)
#pragma unroll
    for (int j = 0; j < 4; ++j) acc[i][j] = (f32x4){0.f, 0.f, 0.f, 0.f};

  for (int k0 = 0; k0 < 1024; k0 += 64) {
#pragma unroll
    for (int i = 0; i < 4; ++i) {
      int c = t + i * 256;
      int r = c >> 3, cl = c & 7;
      int cg = cl ^ (r & 7);
      gload_lds16(attnb + (size_t)(row0 + r) * 1024 + k0 + cg * 8, Al + c * 8);
      gload_lds16(Wob   + (size_t)(n0 + r) * 1024 + k0 + cg * 8, Bl + c * 8);
    }
    __syncthreads();
#pragma unroll
    for (int ks = 0; ks < 2; ++ks) {
      const int kb8 = (ks * 4 + lq) * 8;
      s8v af[4], bfr[4];
#pragma unroll
      for (int i = 0; i < 4; ++i)
        af[i] = *(s8v*)&Al[(wm * 64 + i * 16 + l15) * 64 + (kb8 ^ sx)];
#pragma unroll
      for (int j = 0; j < 4; ++j)
        bfr[j] = *(s8v*)&Bl[(wn * 64 + j * 16 + l15) * 64 + (kb8 ^ sx)];
#pragma unroll
      for (int i = 0; i < 4; ++i)
#pragma unroll
        for (int j = 0; j < 4; ++j)
          acc[i][j] = MFMA_BF16(af[i], bfr[j], acc[i][j]);
    }
    __syncthreads();
  }

#pragma unroll
  for (int j = 0; j < 4; ++j) {
    int cl = wn * 64 + j * 16 + l15;
    float bsv = bo_[n0 + cl];
#pragma unroll
    for (int i = 0; i < 4; ++i)
#pragma unroll
      for (int r = 0; r < 4; ++r)
        out[(size_t)(row0 + wm * 64 + i * 16 + lq * 4 + r) * 1024 + n0 + cl] =
            acc[i][j][r] + bsv;
  }
}

// ---------------------------------------------------------------------------
extern "C" void kernel_launch(void* const* d_in, const int* in_sizes, int n_in,
                              void* d_out, int out_size, void* d_ws, size_t ws_size,
                              hipStream_t stream) {
  const float* x    = (const float*)d_in[0];
  const float* proj = (const float*)d_in[1];
  const float* Wq   = (const float*)d_in[2];
  const float* bq   = (const float*)d_in[3];
  const float* Wk   = (const float*)d_in[4];
  const float* bk   = (const float*)d_in[5];
  const float* Wv   = (const float*)d_in[6];
  const float* bv   = (const float*)d_in[7];
  const float* Wo   = (const float*)d_in[8];
  const float* bo   = (const float*)d_in[9];
  float* out = (float*)d_out;

  char* wsb = (char*)d_ws;
  short* qb    = (short*)(wsb + 0);
  short* kb    = (short*)(wsb + 33554432);
  short* vT    = (short*)(wsb + 67108864);
  short* xb    = (short*)(wsb + 100663296);
  short* Wqkvb = (short*)(wsb + 134217728);
  short* Wob   = (short*)(wsb + 140509184);
  short* projT = (short*)(wsb + 142606336);
  float* kv_part = (float*)(wsb + 100663296);  // 32MB, overlays xb (dead after K1)
  short* attnb = kb;                            // kb dead after K2
  short* kvT   = vT;                            // vT dead after K2

  conv_all_kernel<<<dim3(2048), dim3(256), 0, stream>>>(
      x, Wq, Wk, Wv, Wo, proj, xb, Wqkvb, Wob, projT);

  qkv_gemm_kernel<<<dim3(128, 24), dim3(256), 0, stream>>>(xb, Wqkvb, bq, bk, bv, qb, kb, vT);
  kv_accum_kernel<<<dim3(512), dim3(256), 0, stream>>>(kb, vT, projT, kv_part);
  kvT_kernel<<<dim3(64, 4), dim3(256), 0, stream>>>(kv_part, kvT);
  attn_kernel<<<dim3(256, 16), dim3(256), 0, stream>>>(qb, projT, kvT, attnb);
  out_gemm_kernel<<<dim3(128, 8), dim3(256), 0, stream>>>(attnb, Wob, bo, out);
}

// Round 7
// 398.145 us; speedup vs baseline: 1.0109x; 1.0109x over previous
//
#include <hip/hip_runtime.h>
#include <cstddef>
#include <cstdint>

// LinearAttention — bf16 MFMA, global_load_lds staging, XOR-swizzled LDS.
// B=4 L=4096 D=1024 H=16 d=64 M=128 (2M=256).
// K0 fused convert (grid-stride) -> K1 fused QKV GEMM (128^2, proven)
// -> K2 fourier(k)+kv outer (private partials, simple sync — proven)
// -> K2.5 reduce+transpose -> K3 fourier(q)+attn (REBUILT: 512thr/128 rows,
// q in regs, kvt staged once, 16 waves/CU) -> K4 out GEMM.
//
// ws layout (bytes):
//   qb     @ 0          33.55MB  bf16 [16384][1024]
//   kb     @ 33554432   33.55MB  bf16 [16384][1024]   (reused as attnb)
//   vT     @ 67108864   33.55MB  bf16 [(b*16+h)*64+d][4096]  (reused as kvT)
//   xb     @ 100663296  33.55MB  bf16 [16384][1024]   (kv_part f32 32MB overlays after K1)
//   Wqkvb  @ 134217728   6.29MB  bf16 [3072][1024]
//   Wob    @ 140509184   2.10MB  bf16 [1024][1024]
//   projT  @ 142606336   16KB    bf16 [128 m][64 d]

typedef __attribute__((ext_vector_type(8))) short s8v;   // 8 x bf16 (16B)
typedef __attribute__((ext_vector_type(4))) short s4v;   // 4 x bf16 (8B)
typedef __attribute__((ext_vector_type(4))) float f32x4; // MFMA acc

#define MFMA_BF16(a, b, c) __builtin_amdgcn_mfma_f32_16x16x32_bf16((a), (b), (c), 0, 0, 0)

#define P_SCALE 0.125f                 // 1/sqrt(64)
#define F_SCALE 0.08838834764831845f   // 1/sqrt(128)

static __device__ __forceinline__ unsigned short f2bf(float f) {
  unsigned int u = __float_as_uint(f);
  u += 0x7fffu + ((u >> 16) & 1u);  // RNE
  return (unsigned short)(u >> 16);
}

// async 16B global->LDS (DMA; LDS dest = wave-uniform base + lane*16)
static __device__ __forceinline__ void gload_lds16(const void* g, void* l) {
  __builtin_amdgcn_global_load_lds(
      (const __attribute__((address_space(1))) unsigned int*)g,
      (__attribute__((address_space(3))) unsigned int*)l, 16, 0, 0);
}

#define VMC(n) asm volatile("s_waitcnt vmcnt(" #n ")" ::: "memory")
#define LGKM0 asm volatile("s_waitcnt lgkmcnt(0)" ::: "memory")
#define RBAR  { __builtin_amdgcn_s_barrier(); __builtin_amdgcn_sched_barrier(0); }

// ---------------------------------------------------------------------------
// K0: fused fp32->bf16 convert, grid-stride (2048 blocks x 256 thr).
// ---------------------------------------------------------------------------
__global__ void conv_all_kernel(const float* __restrict__ x,
                                const float* __restrict__ Wq, const float* __restrict__ Wk,
                                const float* __restrict__ Wv, const float* __restrict__ Wo,
                                const float* __restrict__ proj,
                                short* __restrict__ xb, short* __restrict__ Wqkvb,
                                short* __restrict__ Wob, short* __restrict__ projT) {
  const int T = blockIdx.x * 256 + threadIdx.x;  // 0..524287
  for (int u = T; u < 5244928; u += 524288) {
    if (u < 4194304) {
      float4 f = ((const float4*)x)[u];
      s4v v;
      v[0] = (short)f2bf(f.x); v[1] = (short)f2bf(f.y);
      v[2] = (short)f2bf(f.z); v[3] = (short)f2bf(f.w);
      ((s4v*)xb)[u] = v;
    } else if (u < 5242880) {
      int vi = u - 4194304;
      int wi = vi >> 18;           // 0..3 (Wq,Wk,Wv,Wo), 262144 float4 each
      int off = vi & 262143;
      const float* src = (wi == 0) ? Wq : (wi == 1) ? Wk : (wi == 2) ? Wv : Wo;
      short* dst = (wi < 3) ? (Wqkvb + (size_t)wi * 1048576) : Wob;
      float4 f = ((const float4*)src)[off];
      s4v v;
      v[0] = (short)f2bf(f.x); v[1] = (short)f2bf(f.y);
      v[2] = (short)f2bf(f.z); v[3] = (short)f2bf(f.w);
      ((s4v*)dst)[off] = v;
    } else {
      int vi = u - 5242880;        // proj [64 d][128 m]: 32 float4 per row
      int d = vi >> 5, m4 = (vi & 31) * 4;
      float4 f = ((const float4*)proj)[vi];
      projT[(m4 + 0) * 64 + d] = (short)f2bf(f.x);
      projT[(m4 + 1) * 64 + d] = (short)f2bf(f.y);
      projT[(m4 + 2) * 64 + d] = (short)f2bf(f.z);
      projT[(m4 + 3) * 64 + d] = (short)f2bf(f.w);
    }
  }
}

// ---------------------------------------------------------------------------
// K1: qkv = xb @ Wqkv^T + bias. 128x128 tile, BK=64, bf16 MFMA. (Proven:
// ~104us, 45% MfmaUtil; 256^2 8-phase ports measured SLOWER: 138/110us.)
// grid (128 row-tiles, 24 col-tiles). bn 0-7: q, 8-15: k, 16-23: v.
// ---------------------------------------------------------------------------
__global__ void qkv_gemm_kernel(const short* __restrict__ xb,
                                const short* __restrict__ Wqkv,
                                const float* __restrict__ bq_, const float* __restrict__ bk_,
                                const float* __restrict__ bv_,
                                short* __restrict__ qb, short* __restrict__ kb,
                                short* __restrict__ vT) {
  __shared__ __align__(16) short smem[17408];  // A[128][64]+B[128][64]; epi image [128][136]
  short* Al = smem;
  short* Bl = smem + 8192;

  const int t = threadIdx.x;
  const int bm = blockIdx.x, bn = blockIdx.y;
  const int row0 = bm * 128, n0 = bn * 128;
  const int lane = t & 63, w = t >> 6;
  const int wm = w & 1, wn = w >> 1;
  const int l15 = lane & 15, lq = lane >> 4;
  const int sx = (l15 & 7) * 8;   // fragment-read swizzle term (in shorts)

  f32x4 acc[4][4];
#pragma unroll
  for (int i = 0; i < 4; ++i)
#pragma unroll
    for (int j = 0; j < 4; ++j) acc[i][j] = (f32x4){0.f, 0.f, 0.f, 0.f};

  for (int k0 = 0; k0 < 1024; k0 += 64) {
#pragma unroll
    for (int i = 0; i < 4; ++i) {
      int c = t + i * 256;                 // chunk 0..1023
      int r = c >> 3, cl = c & 7;
      int cg = cl ^ (r & 7);               // permuted global chunk
      gload_lds16(xb   + (size_t)(row0 + r) * 1024 + k0 + cg * 8, Al + c * 8);
      gload_lds16(Wqkv + (size_t)(n0 + r) * 1024 + k0 + cg * 8, Bl + c * 8);
    }
    __syncthreads();
#pragma unroll
    for (int ks = 0; ks < 2; ++ks) {
      const int kb8 = (ks * 4 + lq) * 8;
      s8v af[4], bfr[4];
#pragma unroll
      for (int i = 0; i < 4; ++i)
        af[i] = *(s8v*)&Al[(wm * 64 + i * 16 + l15) * 64 + (kb8 ^ sx)];
#pragma unroll
      for (int j = 0; j < 4; ++j)
        bfr[j] = *(s8v*)&Bl[(wn * 64 + j * 16 + l15) * 64 + (kb8 ^ sx)];
#pragma unroll
      for (int i = 0; i < 4; ++i)
#pragma unroll
        for (int j = 0; j < 4; ++j)
          acc[i][j] = MFMA_BF16(af[i], bfr[j], acc[i][j]);
    }
    __syncthreads();
  }

  const int region = bn >> 3;  // 0 q, 1 k, 2 v
  if (region < 2) {
    const float* bias = (region == 0) ? bq_ : bk_;
    short* IM = smem;  // [128][136] natural image
#pragma unroll
    for (int j = 0; j < 4; ++j) {
      int cl = wn * 64 + j * 16 + l15;
      float bsv = bias[(n0 & 1023) + cl];
#pragma unroll
      for (int i = 0; i < 4; ++i)
#pragma unroll
        for (int r = 0; r < 4; ++r)
          IM[(wm * 64 + i * 16 + lq * 4 + r) * 136 + cl] = (short)f2bf(acc[i][j][r] + bsv);
    }
    __syncthreads();
    short* dst = (region == 0) ? qb : kb;
#pragma unroll
    for (int i = 0; i < 8; ++i) {
      int c = t + i * 256;
      int r = c >> 4, cc = c & 15;
      *(s8v*)&dst[(size_t)(row0 + r) * 1024 + (n0 & 1023) + cc * 8] =
          *(s8v*)&IM[r * 136 + cc * 8];
    }
  } else {
    short* IM = smem;  // [128 col][136] transposed image
#pragma unroll
    for (int j = 0; j < 4; ++j) {
      int cl = wn * 64 + j * 16 + l15;
      float bsv = bv_[(n0 - 2048) + cl];
#pragma unroll
      for (int i = 0; i < 4; ++i) {
        s4v pk;
#pragma unroll
        for (int r = 0; r < 4; ++r) pk[r] = (short)f2bf(acc[i][j][r] + bsv);
        *(s4v*)&IM[cl * 136 + wm * 64 + i * 16 + lq * 4] = pk;
      }
    }
    __syncthreads();
    const int b = row0 >> 12;
    const int l0 = (bm & 31) * 128;
#pragma unroll
    for (int i = 0; i < 8; ++i) {
      int c = t + i * 256;
      int ci = c >> 4, cc = c & 15;
      int cv = (bn - 16) * 128 + ci;      // 0..1023
      int grow = (b * 16 + (cv >> 6)) * 64 + (cv & 63);
      *(s8v*)&vT[(size_t)grow * 4096 + l0 + cc * 8] = *(s8v*)&IM[ci * 136 + cc * 8];
    }
  }
}

// ---------------------------------------------------------------------------
// K2: per (b,h,512-row chunk): fourier(k) -> k' ; kv_part[chunk] = k'^T @ v
// (MFMA, private per-block output). grid 512. (Round-5 proven version; the
// dbuf/counted-vmcnt variant measured neutral-to-negative.)
// kv_part layout: [chunk 8][bh 64][m 256][d 64] f32 (32MB, overlays dead xb).
// ---------------------------------------------------------------------------
__global__ void kv_accum_kernel(const short* __restrict__ kb, const short* __restrict__ vT,
                                const short* __restrict__ projT, float* __restrict__ kv) {
  __shared__ __align__(16) short smem[26624];  // kt[64][64]+vt[64][64]+kpT[256][72]
  short* kt = smem;
  short* vt = smem + 4096;
  short* kpT = smem + 8192;

  const int t = threadIdx.x;
  const int bid = blockIdx.x;
  const int chunk = bid & 7, h = (bid >> 3) & 15, b = bid >> 7;
  const int lane = t & 63, w = t >> 6;
  const int l15 = lane & 15, lq = lane >> 4;
  const int sx = (l15 & 7) * 8;

  s8v pf[8][2];
#pragma unroll
  for (int nt = 0; nt < 8; ++nt)
#pragma unroll
    for (int ks = 0; ks < 2; ++ks)
      pf[nt][ks] = *(const s8v*)(projT + (size_t)(nt * 16 + l15) * 64 + ks * 32 + lq * 8);

  f32x4 kvacc[4][4];
#pragma unroll
  for (int i = 0; i < 4; ++i)
#pragma unroll
    for (int j = 0; j < 4; ++j) kvacc[i][j] = (f32x4){0.f, 0.f, 0.f, 0.f};

  for (int s = 0; s < 8; ++s) {
    const int l0s = chunk * 512 + s * 64;
#pragma unroll
    for (int i = 0; i < 2; ++i) {
      int c = t + i * 256;                 // chunk 0..511
      int r = c >> 3, cl = c & 7;
      int cg = cl ^ (r & 7);
      gload_lds16(kb + (size_t)(b * 4096 + l0s + r) * 1024 + h * 64 + cg * 8, kt + c * 8);
      gload_lds16(vT + (size_t)((b * 16 + h) * 64 + r) * 4096 + l0s + cg * 8, vt + c * 8);
    }
    __syncthreads();

    // fourier: wave w rows w*16..+15
    f32x4 pacc[8];
#pragma unroll
    for (int nt = 0; nt < 8; ++nt) pacc[nt] = (f32x4){0.f, 0.f, 0.f, 0.f};
#pragma unroll
    for (int ks = 0; ks < 2; ++ks) {
      const int kb8 = (ks * 4 + lq) * 8;
      s8v af = *(s8v*)&kt[(w * 16 + l15) * 64 + (kb8 ^ sx)];
#pragma unroll
      for (int nt = 0; nt < 8; ++nt) pacc[nt] = MFMA_BF16(af, pf[nt][ks], pacc[nt]);
    }
#pragma unroll
    for (int nt = 0; nt < 8; ++nt) {
      s4v cp, sp;
#pragma unroll
      for (int r = 0; r < 4; ++r) {
        float pv = pacc[nt][r] * P_SCALE;
        float sv, cv;
        __sincosf(pv, &sv, &cv);
        cp[r] = (short)f2bf(cv * F_SCALE);
        sp[r] = (short)f2bf(sv * F_SCALE);
      }
      int m = nt * 16 + l15;
      int rbase = w * 16 + lq * 4;
      *(s4v*)&kpT[m * 72 + rbase] = cp;
      *(s4v*)&kpT[(m + 128) * 72 + rbase] = sp;
    }
    __syncthreads();

    // kv MFMA: wave w m-range w*64..+63
#pragma unroll
    for (int ks = 0; ks < 2; ++ks) {
      const int kb8 = (ks * 4 + lq) * 8;
      s8v af[4], bf4[4];
#pragma unroll
      for (int i = 0; i < 4; ++i)
        af[i] = *(s8v*)&kpT[(w * 64 + i * 16 + l15) * 72 + ks * 32 + lq * 8];
#pragma unroll
      for (int j = 0; j < 4; ++j)
        bf4[j] = *(s8v*)&vt[(j * 16 + l15) * 64 + (kb8 ^ sx)];
#pragma unroll
      for (int i = 0; i < 4; ++i)
#pragma unroll
        for (int j = 0; j < 4; ++j)
          kvacc[i][j] = MFMA_BF16(af[i], bf4[j], kvacc[i][j]);
    }
    __syncthreads();
  }

  // private partial: kv_part[chunk][bh][m][d], plain coalesced stores
  float* kvb = kv + (size_t)chunk * 1048576 + ((size_t)(b * 16 + h) << 14);
#pragma unroll
  for (int i = 0; i < 4; ++i)
#pragma unroll
    for (int j = 0; j < 4; ++j)
#pragma unroll
      for (int r = 0; r < 4; ++r) {
        int m = w * 64 + i * 16 + lq * 4 + r;
        int d = j * 16 + l15;
        kvb[(size_t)m * 64 + d] = kvacc[i][j][r];
      }
}

// ---------------------------------------------------------------------------
// K2.5: reduce 8 kv partials f32 -> kvT bf16 [bh*64+d][256]. grid (64,4).
// ---------------------------------------------------------------------------
__global__ void kvT_kernel(const float* __restrict__ kvp, short* __restrict__ kvT) {
  __shared__ __align__(16) short im[4608];  // [64 d][72]
  const int t = threadIdx.x;
  const int bh = blockIdx.x, mc = blockIdx.y;
  const float* base = kvp + (size_t)bh * 16384 + (size_t)mc * 4096;
#pragma unroll
  for (int i = 0; i < 4; ++i) {
    int idx4 = t + i * 256;                // 1024 float4s = [64 m][64 d]
    int mm = idx4 >> 4, d4 = (idx4 & 15) * 4;
    float4 s = {0.f, 0.f, 0.f, 0.f};
#pragma unroll
    for (int c = 0; c < 8; ++c) {
      float4 v = *(const float4*)(base + (size_t)c * 1048576 + mm * 64 + d4);
      s.x += v.x; s.y += v.y; s.z += v.z; s.w += v.w;
    }
    im[(d4 + 0) * 72 + mm] = (short)f2bf(s.x);
    im[(d4 + 1) * 72 + mm] = (short)f2bf(s.y);
    im[(d4 + 2) * 72 + mm] = (short)f2bf(s.z);
    im[(d4 + 3) * 72 + mm] = (short)f2bf(s.w);
  }
  __syncthreads();
#pragma unroll
  for (int i = 0; i < 2; ++i) {
    int c = t + i * 256;                   // 512 stores x 16B = [64 d][64 m]
    int d = c >> 3, mm8 = (c & 7) * 8;
    *(s8v*)&kvT[(size_t)(bh * 64 + d) * 256 + mc * 64 + mm8] = *(s8v*)&im[d * 72 + mm8];
  }
}

// ---------------------------------------------------------------------------
// K3: fourier(q) + attn = q' @ kv. REBUILT: 512 thr (8 waves), 128 rows/block,
// grid (128,16). q A-fragments loaded DIRECT to registers (no qt stage).
// kvt both halves staged once per block via gload_lds; counted VMC(2)/VMC(0).
// LDS 66KB: qA[128][136] + kvt[2][64][128] -> 2 blocks/CU = 16 waves/CU.
// ---------------------------------------------------------------------------
__global__ void attn_kernel(const short* __restrict__ qb, const short* __restrict__ projT,
                            const short* __restrict__ kvT, short* __restrict__ attnb) {
  __shared__ __align__(16) short smem[33792];  // qA 17408 + kvt 16384 shorts
  short* qA = smem;             // [128][136]
  short* kvt = smem + 17408;    // [2][64][128]

  const int t = threadIdx.x;
  const int rt = blockIdx.x, h = blockIdx.y;
  const int row0 = rt * 128;
  const int b = row0 >> 12;
  const int lane = t & 63, w = t >> 6;       // 8 waves
  const int l15 = lane & 15, lq = lane >> 4;

  s8v pf[8][2];
#pragma unroll
  for (int nt = 0; nt < 8; ++nt)
#pragma unroll
    for (int ks = 0; ks < 2; ++ks)
      pf[nt][ks] = *(const s8v*)(projT + (size_t)(nt * 16 + l15) * 64 + ks * 32 + lq * 8);

  // q A-fragment direct to regs (issued FIRST -> retires at vmcnt(4))
  s8v qf[2];
#pragma unroll
  for (int ks = 0; ks < 2; ++ks)
    qf[ks] = *(const s8v*)&qb[(size_t)(row0 + w * 16 + l15) * 1024 + h * 64 +
                              (ks * 4 + lq) * 8];

  // stage kvt both halves (4 gload_lds/thread, stay in flight under fourier)
#pragma unroll
  for (int half = 0; half < 2; ++half)
#pragma unroll
    for (int i = 0; i < 2; ++i) {
      int c = t + i * 512;                 // chunk 0..1023
      int d = c >> 4, cl = c & 15;
      int cg = cl ^ (d & 15);
      gload_lds16(kvT + (size_t)((b * 16 + h) * 64 + d) * 256 + half * 128 + cg * 8,
                  kvt + half * 8192 + c * 8);
    }

  // fourier (register-only inputs; compiler waits qf at vmcnt(4))
  f32x4 pacc[8];
#pragma unroll
  for (int nt = 0; nt < 8; ++nt) pacc[nt] = (f32x4){0.f, 0.f, 0.f, 0.f};
#pragma unroll
  for (int ks = 0; ks < 2; ++ks)
#pragma unroll
    for (int nt = 0; nt < 8; ++nt) pacc[nt] = MFMA_BF16(qf[ks], pf[nt][ks], pacc[nt]);

  f32x4 aacc[4];
#pragma unroll
  for (int j = 0; j < 4; ++j) aacc[j] = (f32x4){0.f, 0.f, 0.f, 0.f};

#pragma unroll
  for (int half = 0; half < 2; ++half) {
    // q' half -> qA (wave-private rows w*16..+15)
#pragma unroll
    for (int nt = 0; nt < 8; ++nt)
#pragma unroll
      for (int r = 0; r < 4; ++r) {
        float p = pacc[nt][r] * P_SCALE;
        float fv = (half == 0) ? __cosf(p) : __sinf(p);
        qA[(w * 16 + lq * 4 + r) * 136 + nt * 16 + l15] = (short)f2bf(fv * F_SCALE);
      }
    LGKM0;                                   // own qA writes landed
    if (half == 0) { VMC(2); } else { VMC(0); }
    RBAR;                                    // kvt[half] staged by all waves
#pragma unroll
    for (int ks = 0; ks < 4; ++ks) {
      s8v af = *(s8v*)&qA[(w * 16 + l15) * 136 + ks * 32 + lq * 8];
#pragma unroll
      for (int j = 0; j < 4; ++j) {
        int row = j * 16 + l15;
        s8v bf4 = *(s8v*)&kvt[half * 8192 + row * 128 + (((ks * 4 + lq) ^ l15) * 8)];
        aacc[j] = MFMA_BF16(af, bf4, aacc[j]);
      }
    }
    if (half == 0) RBAR;                     // qA consumed before half1 rewrite
  }

  // epilogue image [128][72] at smem base (own-wave rows only -> no pre-barrier)
#pragma unroll
  for (int j = 0; j < 4; ++j)
#pragma unroll
    for (int r = 0; r < 4; ++r)
      smem[(w * 16 + lq * 4 + r) * 72 + j * 16 + l15] = (short)f2bf(aacc[j][r]);
  __syncthreads();
#pragma unroll
  for (int i = 0; i < 2; ++i) {
    int c = t + i * 512;                     // 1024 chunks = [128 r][8 cc]
    int r = c >> 3, cc = c & 7;
    *(s8v*)&attnb[(size_t)(row0 + r) * 1024 + h * 64 + cc * 8] = *(s8v*)&smem[r * 72 + cc * 8];
  }
}

// ---------------------------------------------------------------------------
// K4: out = attn @ Wo^T + bo. fp32 out. grid (128, 8).
// ---------------------------------------------------------------------------
__global__ void out_gemm_kernel(const short* __restrict__ attnb, const short* __restrict__ Wob,
                                const float* __restrict__ bo_, float* __restrict__ out) {
  __shared__ __align__(16) short smem[16384];
  short* Al = smem;
  short* Bl = smem + 8192;

  const int t = threadIdx.x;
  const int bm = blockIdx.x, bn = blockIdx.y;
  const int row0 = bm * 128, n0 = bn * 128;
  const int lane = t & 63, w = t >> 6;
  const int wm = w & 1, wn = w >> 1;
  const int l15 = lane & 15, lq = lane >> 4;
  const int sx = (l15 & 7) * 8;

  f32x4 acc[4][4];
#pragma unroll
  for (int i = 0; i < 4; ++i)
#pragma unroll
    for (int j = 0; j < 4; ++j) acc[i][j] = (f32x4){0.f, 0.f, 0.f, 0.f};

  for (int k0 = 0; k0 < 1024; k0 += 64) {
#pragma unroll
    for (int i = 0; i < 4; ++i) {
      int c = t + i * 256;
      int r = c >> 3, cl = c & 7;
      int cg = cl ^ (r & 7);
      gload_lds16(attnb + (size_t)(row0 + r) * 1024 + k0 + cg * 8, Al + c * 8);
      gload_lds16(Wob   + (size_t)(n0 + r) * 1024 + k0 + cg * 8, Bl + c * 8);
    }
    __syncthreads();
#pragma unroll
    for (int ks = 0; ks < 2; ++ks) {
      const int kb8 = (ks * 4 + lq) * 8;
      s8v af[4], bfr[4];
#pragma unroll
      for (int i = 0; i < 4; ++i)
        af[i] = *(s8v*)&Al[(wm * 64 + i * 16 + l15) * 64 + (kb8 ^ sx)];
#pragma unroll
      for (int j = 0; j < 4; ++j)
        bfr[j] = *(s8v*)&Bl[(wn * 64 + j * 16 + l15) * 64 + (kb8 ^ sx)];
#pragma unroll
      for (int i = 0; i < 4; ++i)
#pragma unroll
        for (int j = 0; j < 4; ++j)
          acc[i][j] = MFMA_BF16(af[i], bfr[j], acc[i][j]);
    }
    __syncthreads();
  }

#pragma unroll
  for (int j = 0; j < 4; ++j) {
    int cl = wn * 64 + j * 16 + l15;
    float bsv = bo_[n0 + cl];
#pragma unroll
    for (int i = 0; i < 4; ++i)
#pragma unroll
      for (int r = 0; r < 4; ++r)
        out[(size_t)(row0 + wm * 64 + i * 16 + lq * 4 + r) * 1024 + n0 + cl] =
            acc[i][j][r] + bsv;
  }
}

// ---------------------------------------------------------------------------
extern "C" void kernel_launch(void* const* d_in, const int* in_sizes, int n_in,
                              void* d_out, int out_size, void* d_ws, size_t ws_size,
                              hipStream_t stream) {
  const float* x    = (const float*)d_in[0];
  const float* proj = (const float*)d_in[1];
  const float* Wq   = (const float*)d_in[2];
  const float* bq   = (const float*)d_in[3];
  const float* Wk   = (const float*)d_in[4];
  const float* bk   = (const float*)d_in[5];
  const float* Wv   = (const float*)d_in[6];
  const float* bv   = (const float*)d_in[7];
  const float* Wo   = (const float*)d_in[8];
  const float* bo   = (const float*)d_in[9];
  float* out = (float*)d_out;

  char* wsb = (char*)d_ws;
  short* qb    = (short*)(wsb + 0);
  short* kb    = (short*)(wsb + 33554432);
  short* vT    = (short*)(wsb + 67108864);
  short* xb    = (short*)(wsb + 100663296);
  short* Wqkvb = (short*)(wsb + 134217728);
  short* Wob   = (short*)(wsb + 140509184);
  short* projT = (short*)(wsb + 142606336);
  float* kv_part = (float*)(wsb + 100663296);  // 32MB, overlays xb (dead after K1)
  short* attnb = kb;                            // kb dead after K2
  short* kvT   = vT;                            // vT dead after K2

  conv_all_kernel<<<dim3(2048), dim3(256), 0, stream>>>(
      x, Wq, Wk, Wv, Wo, proj, xb, Wqkvb, Wob, projT);

  qkv_gemm_kernel<<<dim3(128, 24), dim3(256), 0, stream>>>(xb, Wqkvb, bq, bk, bv, qb, kb, vT);
  kv_accum_kernel<<<dim3(512), dim3(256), 0, stream>>>(kb, vT, projT, kv_part);
  kvT_kernel<<<dim3(64, 4), dim3(256), 0, stream>>>(kv_part, kvT);
  attn_kernel<<<dim3(128, 16), dim3(512), 0, stream>>>(qb, projT, kvT, attnb);
  out_gemm_kernel<<<dim3(128, 8), dim3(256), 0, stream>>>(attnb, Wob, bo, out);
}